// Round 1
// 837.201 us; speedup vs baseline: 1.1248x; 1.1248x over previous
//
#include <hip/hip_runtime.h>

// ---------------------------------------------------------------------------
// MoE FFN (SwiGLU, top-2 of 8 + shared expert), MI355X gfx950.
// R5: both GEMMs ported to the 256x256xBK64 8-wave 8-phase schedule
//     (T2 lds-swizzle + T3/T4 counted-vmcnt pipeline + T5 setprio).
//     gemm1 dual-B removed via 32-col W1/W3 interleave -> in-register
//     silu-combine; 128 KiB LDS, vmcnt(10) steady state, never vmcnt(0)
//     inside the K-loop.
// ---------------------------------------------------------------------------

#define T_TOK 8192
#define DDIM  1024
#define HDIM  2048
#define NEXP  8
#define NSLOT 24576        // 2*T routed + T shared
#define NROUTED 16384
#define MAX_T 104          // 256-row tiles: 32 shared + <=71 routed (+pad)
#define NT1 16             // gemm1 K=1024 / 64
#define NT2 32             // gemm2 K=2048 / 64

typedef __attribute__((ext_vector_type(8))) __bf16 bf16x8;
typedef __attribute__((ext_vector_type(4))) __bf16 bf16x4;
typedef __attribute__((ext_vector_type(4))) float  f32x4;

__device__ __forceinline__ void gload16(const void* g, void* l) {
  __builtin_amdgcn_global_load_lds(
      (const __attribute__((address_space(1))) void*)g,
      (__attribute__((address_space(3))) void*)l, 16, 0, 0);
}

#define BAR()   __builtin_amdgcn_s_barrier()
#define VMW10() asm volatile("s_waitcnt vmcnt(10)" ::: "memory")
#define VMW0()  asm volatile("s_waitcnt vmcnt(0)" ::: "memory")
#define LGKM0() asm volatile("s_waitcnt lgkmcnt(0)" ::: "memory")

// ---------------- fused fp32 -> bf16 convert (all 7 tensors, 1 launch) -----
// W1/sw1/W3/sw3 are written into the interleaved w13 layout:
//   row c of B-panel (e,nb):  c = ((h>>5)&3)*64 + sel*32 + (h&31), nb = h>>7
// so that a 64-col wave slice holds [W1 slice | W3 same slice].
struct CvtArgs { const float* s[7]; __bf16* d[7]; };

__global__ __launch_bounds__(256) void cvt_fused(CvtArgs a) {
  // vec4 cumulative bounds: h, W1, sw1, W3, sw3, W2, sw2
  constexpr long cum[8] = {0, 2097152, 6291456, 6815744, 11010048,
                           11534336, 15728640, 16252928};
  long i = (long)blockIdx.x * 256 + threadIdx.x;
  if (i >= cum[7]) return;
  int r = 0;
#pragma unroll
  for (int k = 1; k < 7; k++) if (i >= cum[k]) r = k;
  long o = i - cum[r];
  f32x4 v = ((const f32x4*)a.s[r])[o];
  bf16x4 w;
  w[0] = (__bf16)v[0]; w[1] = (__bf16)v[1];
  w[2] = (__bf16)v[2]; w[3] = (__bf16)v[3];
  if (r >= 1 && r <= 4) {
    int sel  = (r >= 3);
    long e   = (r == 2 || r == 4) ? 8 : (o >> 19);
    long oo  = o & 524287;
    int d4   = (int)(oo & 255);
    int hrow = (int)(oo >> 8) & 2047;
    long c   = ((hrow >> 5) & 3) * 64 + sel * 32 + (hrow & 31);
    long dst = ((e * 16 + (hrow >> 7)) * 256 + c) * 256 + d4;
    ((bf16x4*)a.d[1])[dst] = w;
  } else {
    ((bf16x4*)a.d[r])[o] = w;
  }
}

// ---------------- gate: softmax -> top2 -> renorm (fp32 exact) -------------
__global__ __launch_bounds__(256) void gate_kernel(
    const float* __restrict__ h, const float* __restrict__ Wg,
    int* __restrict__ top_e, float* __restrict__ top_w, int* __restrict__ counts) {
  int wv = threadIdx.x >> 6, lane = threadIdx.x & 63;
  int t = blockIdx.x * 4 + wv;
  const float* x = h + (size_t)t * DDIM;
  float acc[NEXP];
#pragma unroll
  for (int e = 0; e < NEXP; e++) acc[e] = 0.f;
  for (int i = lane; i < DDIM; i += 64) {
    float xv = x[i];
#pragma unroll
    for (int e = 0; e < NEXP; e++) acc[e] = fmaf(xv, Wg[e * DDIM + i], acc[e]);
  }
#pragma unroll
  for (int e = 0; e < NEXP; e++) {
#pragma unroll
    for (int off = 32; off > 0; off >>= 1) acc[e] += __shfl_xor(acc[e], off);
  }
  if (lane == 0) {
    int i1 = 0; float v1 = acc[0];
#pragma unroll
    for (int e = 1; e < NEXP; e++) if (acc[e] > v1) { v1 = acc[e]; i1 = e; }
    int i2 = -1; float v2 = -1e30f;
#pragma unroll
    for (int e = 0; e < NEXP; e++) if (e != i1 && acc[e] > v2) { v2 = acc[e]; i2 = e; }
    float e2 = __expf(v2 - v1);
    float w1 = 1.f / (1.f + e2);
    top_e[2 * t] = i1; top_e[2 * t + 1] = i2;
    top_w[2 * t] = w1; top_w[2 * t + 1] = e2 * w1;
    atomicAdd(&counts[i1], 1);
    atomicAdd(&counts[i2], 1);
  }
}

// ---------------- offsets + tile table (one wave), 256-row tiles -----------
__global__ void build_meta(int* __restrict__ meta, int4* __restrict__ table1) {
  __shared__ int toff[NEXP + 1];
  int lane = threadIdx.x;
  int* counts = meta; int* cursor = meta + 16; int* offsets = meta + 32;
  if (lane == 0) {
    int off = 0, tf = 32;          // shared tiles occupy [0,32)
    for (int e = 0; e < NEXP; e++) {
      offsets[e] = off; cursor[e] = 0;
      toff[e] = tf;
      tf += (counts[e] + 255) >> 8;
      off += counts[e];
    }
    toff[NEXP] = tf;
  }
  __syncthreads();
  for (int i = lane; i < MAX_T; i += 64) {
    if (i < 32) {
      table1[i] = make_int4(NEXP, NROUTED + i * 256, 256, 0);
    } else if (i < toff[NEXP]) {
      int e = 0;
#pragma unroll
      for (int k = 1; k < NEXP; k++) if (i >= toff[k]) e = k;
      int lt = i - toff[e];
      int c = counts[e];
      table1[i] = make_int4(e, offsets[e] + lt * 256, min(256, c - lt * 256), 0);
    } else {
      table1[i] = make_int4(-1, 0, 0, 0);
    }
  }
}

// ---------------- scatter: ballot-ordered per-expert slot lists ------------
__global__ __launch_bounds__(256) void scatter_kernel(
    const int* __restrict__ top_e, const float* __restrict__ top_w,
    int* __restrict__ meta, int* __restrict__ slot_token, float* __restrict__ slot_w,
    int* __restrict__ slot_pos) {
  int t = blockIdx.x * 256 + threadIdx.x;
  int lane = threadIdx.x & 63;
  int* cursor = meta + 16; const int* offsets = meta + 32;
#pragma unroll
  for (int k = 0; k < 2; k++) {
    int e = top_e[2 * t + k];
    unsigned long long same = 0;
#pragma unroll
    for (int ee = 0; ee < NEXP; ee++) {
      unsigned long long m = __ballot(e == ee);
      if (ee == e) same = m;
    }
    int leader = __ffsll((long long)same) - 1;
    int base = 0;
    if (lane == leader) base = atomicAdd(&cursor[e], __popcll(same));
    base = __shfl(base, leader);
    int pos = offsets[e] + base + (int)__popcll(same & ((1ull << lane) - 1ull));
    slot_token[pos] = t; slot_w[pos] = top_w[2 * t + k];
    slot_pos[2 * t + k] = pos;
  }
  slot_token[NROUTED + t] = t;
}

// ---------------- GEMM1: G = silu(A W1^T) * (A W3^T), 8-phase 256x256 ------
// 8 waves (2m x 4n), wave tile 128x64 (= 32 W1-cols + 32 W3-cols of the same
// G slice). LDS: 2 dbuf x {A,B} x 2 kk-halves x [256][32] bf16 = 128 KiB.
__global__ __launch_bounds__(512, 2) void gemm1_k(
    const __bf16* __restrict__ Abase, const __bf16* __restrict__ Wb,
    const int4* __restrict__ table, const int* __restrict__ slot_token,
    __bf16* __restrict__ Gout) {
  int b = blockIdx.x;
  int j = (b & 7) * (MAX_T * 16 / 8) + (b >> 3);   // XCD swizzle (bijective)
  int tile = j >> 4, nb = j & 15;
  int4 te = table[tile];
  if (te.x < 0) return;
  const int expert = te.x, slot0 = te.y, rows = te.z;
  const int tid = threadIdx.x, lane = tid & 63, wave = tid >> 6;
  const int wm = wave >> 2, wn = wave & 3;
  const int ln = lane & 15, q = lane >> 4;

  __shared__ __align__(16) unsigned char lds[131072];

  // staging: thread -> row r0/r0+128, 16B chunk cc; source pre-swizzled
  const int r0 = tid >> 2, cc = tid & 3;
  const int koff = (cc ^ (r0 & 3)) << 3;
  const __bf16* ap0 = Abase + (size_t)slot_token[slot0 + min(r0, rows - 1)] * DDIM + koff;
  const __bf16* ap1 = Abase + (size_t)slot_token[slot0 + min(r0 + 128, rows - 1)] * DDIM + koff;
  const __bf16* bp0 = Wb + (((size_t)expert * 16 + nb) * 256 + r0) * DDIM + koff;
  const __bf16* bp1 = bp0 + 128 * DDIM;
  unsigned char* sb = lds + wave * 1024;

  // frag read bases (swizzled), within a [256][32] kk-half
  const unsigned afo = (wm * 128 + ln) * 64 + ((q ^ (ln & 3)) << 4);
  const unsigned bfo = (wn * 64 + ln) * 64 + ((q ^ (ln & 3)) << 4) + 32768;

  f32x4 acc[8][4] = {};
  bf16x8 afr[4], bfr[4];

  auto SA = [&](int kt, int kk) {
    int ko = min(kt, NT1 - 1) * 64 + kk * 32;
    unsigned char* d = sb + (kt & 1) * 65536 + kk * 16384;
    gload16(ap0 + ko, d); gload16(ap1 + ko, d + 8192);
  };
  auto SB = [&](int kt, int kk) {
    int ko = min(kt, NT1 - 1) * 64 + kk * 32;
    unsigned char* d = sb + (kt & 1) * 65536 + 32768 + kk * 16384;
    gload16(bp0 + ko, d); gload16(bp1 + ko, d + 8192);
  };
  auto RA = [&](int s, int kk, int h) {
#pragma unroll
    for (int i = 0; i < 4; i++)
      afr[i] = *(const bf16x8*)(lds + s * 65536 + kk * 16384 + afo + (h * 4 + i) * 1024);
  };
  auto RB = [&](int s, int kk) {
#pragma unroll
    for (int jj = 0; jj < 4; jj++)
      bfr[jj] = *(const bf16x8*)(lds + s * 65536 + kk * 16384 + bfo + jj * 1024);
  };
  auto MM = [&](int h) {
    __builtin_amdgcn_s_setprio(1);
#pragma unroll
    for (int i = 0; i < 4; i++)
#pragma unroll
      for (int jj = 0; jj < 4; jj++)
        acc[h * 4 + i][jj] = __builtin_amdgcn_mfma_f32_16x16x32_bf16(
            afr[i], bfr[jj], acc[h * 4 + i][jj], 0, 0, 0);
    __builtin_amdgcn_s_setprio(0);
  };

  // prologue: 7 half-tiles in flight; vmcnt(10) leaves 5 newest outstanding
  SA(0, 0); SB(0, 0); SA(0, 1); SB(0, 1);
  SB(1, 0); SA(1, 0); SB(1, 1);
  VMW10(); BAR();

  for (int t = 0; t < NT1; t += 2) {
#pragma unroll
    for (int hb = 0; hb < 2; hb++) {
      const int tt = t + hb, s = hb;
      RB(s, 0); RA(s, 0, 0); SA(tt + 1, 1);
      BAR(); MM(0); BAR();
      RA(s, 0, 1); SB(tt + 2, 0);
      BAR(); MM(1); VMW10(); BAR();
      RB(s, 1); RA(s, 1, 0); SA(tt + 2, 0);
      BAR(); MM(0); BAR();
      RA(s, 1, 1); SB(tt + 2, 1);
      BAR(); MM(1); VMW10(); BAR();
    }
  }

  VMW0(); BAR();   // drain tail garbage stages before LDS reuse

  // epilogue: in-register silu-combine (acc[i][jj] = W1, acc[i][jj+2] = W3,
  // same lane & reg) -> per-wave LDS transpose -> 16B line stores
  __bf16* wbuf = (__bf16*)lds + wave * (128 * 40);
#pragma unroll
  for (int i = 0; i < 8; i++)
#pragma unroll
    for (int jj = 0; jj < 2; jj++)
#pragma unroll
      for (int rg = 0; rg < 4; rg++) {
        float c1 = acc[i][jj][rg], c3 = acc[i][jj + 2][rg];
        float g = (c1 / (1.f + __expf(-c1))) * c3;
        wbuf[(16 * i + 4 * q + rg) * 40 + 16 * jj + ln] = (__bf16)g;
      }
  LGKM0();
  __builtin_amdgcn_sched_barrier(0);
#pragma unroll
  for (int pass = 0; pass < 8; pass++) {
    int rl = pass * 16 + (lane >> 2), ch = lane & 3;
    int grow = wm * 128 + rl;
    if (grow < rows) {
      bf16x8 v = *(const bf16x8*)(wbuf + rl * 40 + ch * 8);
      *(bf16x8*)(Gout + (size_t)(slot0 + grow) * HDIM + nb * 128 + wn * 32 + ch * 8) = v;
    }
  }
}

// ---------------- GEMM2: y_slot = G W2^T, same 8-phase template ------------
__global__ __launch_bounds__(512, 2) void gemm2_k(
    const __bf16* __restrict__ Abase, const __bf16* __restrict__ Bbase,
    const int4* __restrict__ table, __bf16* __restrict__ ys) {
  int b = blockIdx.x;
  int j = (b & 7) * (MAX_T * 4 / 8) + (b >> 3);
  int tile = j >> 2, nb = j & 3;
  int4 te = table[tile];
  if (te.x < 0) return;
  const int expert = te.x, slot0 = te.y, rows = te.z;
  const int tid = threadIdx.x, lane = tid & 63, wave = tid >> 6;
  const int wm = wave >> 2, wn = wave & 3;
  const int ln = lane & 15, q = lane >> 4;

  __shared__ __align__(16) unsigned char lds[131072];

  const int r0 = tid >> 2, cc = tid & 3;
  const int koff = (cc ^ (r0 & 3)) << 3;
  const __bf16* ap0 = Abase + (size_t)(slot0 + min(r0, rows - 1)) * HDIM + koff;
  const __bf16* ap1 = Abase + (size_t)(slot0 + min(r0 + 128, rows - 1)) * HDIM + koff;
  const __bf16* bp0 = Bbase + (size_t)expert * (DDIM * HDIM) +
                      (size_t)(nb * 256 + r0) * HDIM + koff;
  const __bf16* bp1 = bp0 + 128 * HDIM;
  unsigned char* sb = lds + wave * 1024;

  const unsigned afo = (wm * 128 + ln) * 64 + ((q ^ (ln & 3)) << 4);
  const unsigned bfo = (wn * 64 + ln) * 64 + ((q ^ (ln & 3)) << 4) + 32768;

  f32x4 acc[8][4] = {};
  bf16x8 afr[4], bfr[4];

  auto SA = [&](int kt, int kk) {
    int ko = min(kt, NT2 - 1) * 64 + kk * 32;
    unsigned char* d = sb + (kt & 1) * 65536 + kk * 16384;
    gload16(ap0 + ko, d); gload16(ap1 + ko, d + 8192);
  };
  auto SB = [&](int kt, int kk) {
    int ko = min(kt, NT2 - 1) * 64 + kk * 32;
    unsigned char* d = sb + (kt & 1) * 65536 + 32768 + kk * 16384;
    gload16(bp0 + ko, d); gload16(bp1 + ko, d + 8192);
  };
  auto RA = [&](int s, int kk, int h) {
#pragma unroll
    for (int i = 0; i < 4; i++)
      afr[i] = *(const bf16x8*)(lds + s * 65536 + kk * 16384 + afo + (h * 4 + i) * 1024);
  };
  auto RB = [&](int s, int kk) {
#pragma unroll
    for (int jj = 0; jj < 4; jj++)
      bfr[jj] = *(const bf16x8*)(lds + s * 65536 + kk * 16384 + bfo + jj * 1024);
  };
  auto MM = [&](int h) {
    __builtin_amdgcn_s_setprio(1);
#pragma unroll
    for (int i = 0; i < 4; i++)
#pragma unroll
      for (int jj = 0; jj < 4; jj++)
        acc[h * 4 + i][jj] = __builtin_amdgcn_mfma_f32_16x16x32_bf16(
            afr[i], bfr[jj], acc[h * 4 + i][jj], 0, 0, 0);
    __builtin_amdgcn_s_setprio(0);
  };

  SA(0, 0); SB(0, 0); SA(0, 1); SB(0, 1);
  SB(1, 0); SA(1, 0); SB(1, 1);
  VMW10(); BAR();

  for (int t = 0; t < NT2; t += 2) {
#pragma unroll
    for (int hb = 0; hb < 2; hb++) {
      const int tt = t + hb, s = hb;
      RB(s, 0); RA(s, 0, 0); SA(tt + 1, 1);
      BAR(); MM(0); BAR();
      RA(s, 0, 1); SB(tt + 2, 0);
      BAR(); MM(1); VMW10(); BAR();
      RB(s, 1); RA(s, 1, 0); SA(tt + 2, 0);
      BAR(); MM(0); BAR();
      RA(s, 1, 1); SB(tt + 2, 1);
      BAR(); MM(1); VMW10(); BAR();
    }
  }

  VMW0(); BAR();

  // epilogue: 2 m-half passes through a per-wave 64x(64+8) transpose buffer
  __bf16* wbuf = (__bf16*)lds + wave * (64 * 72);
#pragma unroll
  for (int hh = 0; hh < 2; hh++) {
#pragma unroll
    for (int i = 0; i < 4; i++)
#pragma unroll
      for (int jj = 0; jj < 4; jj++)
#pragma unroll
        for (int rg = 0; rg < 4; rg++)
          wbuf[(16 * i + 4 * q + rg) * 72 + 16 * jj + ln] =
              (__bf16)acc[hh * 4 + i][jj][rg];
    LGKM0();
    __builtin_amdgcn_sched_barrier(0);
#pragma unroll
    for (int pass = 0; pass < 8; pass++) {
      int rl = pass * 8 + (lane >> 3), ch = lane & 7;
      int grow = wm * 128 + hh * 64 + rl;
      if (grow < rows) {
        bf16x8 v = *(const bf16x8*)(wbuf + rl * 72 + ch * 8);
        *(bf16x8*)(ys + (size_t)(slot0 + grow) * DDIM + nb * 256 + wn * 64 + ch * 8) = v;
      }
    }
    if (hh == 0) { LGKM0(); __builtin_amdgcn_sched_barrier(0); }
  }
}

// ---------------- combine: y[t] = w1*ys[p1] + w2*ys[p2] + ys[shared] -------
__global__ __launch_bounds__(256) void combine_kernel(
    const __bf16* __restrict__ ys, const int* __restrict__ slot_pos,
    const float* __restrict__ slot_w, float* __restrict__ y) {
  int t = blockIdx.x, d = threadIdx.x * 4;
  int p1 = slot_pos[2 * t], p2 = slot_pos[2 * t + 1];
  float w1 = slot_w[p1], w2 = slot_w[p2];
  bf16x4 a = *(const bf16x4*)(ys + (size_t)p1 * DDIM + d);
  bf16x4 bb = *(const bf16x4*)(ys + (size_t)p2 * DDIM + d);
  bf16x4 c = *(const bf16x4*)(ys + (size_t)(NROUTED + t) * DDIM + d);
  f32x4 o;
#pragma unroll
  for (int i = 0; i < 4; i++)
    o[i] = fmaf(w1, (float)a[i], fmaf(w2, (float)bb[i], (float)c[i]));
  *(f32x4*)(y + (size_t)t * DDIM + d) = o;
}

// ---------------------------------------------------------------------------
extern "C" void kernel_launch(void* const* d_in, const int* in_sizes, int n_in,
                              void* d_out, int out_size, void* d_ws, size_t ws_size,
                              hipStream_t stream) {
  const float* h   = (const float*)d_in[0];
  const float* sw1 = (const float*)d_in[1];
  const float* sw2 = (const float*)d_in[2];
  const float* sw3 = (const float*)d_in[3];
  const float* W1  = (const float*)d_in[4];
  const float* W2  = (const float*)d_in[5];
  const float* W3  = (const float*)d_in[6];
  const float* Wg  = (const float*)d_in[7];
  float* y = (float*)d_out;

  char* ws = (char*)d_ws;
  int*   meta       = (int*)ws;                               // 256 B
  int*   top_e      = (int*)(ws + 256);                       // 64 KB
  float* top_w      = (float*)(ws + 256 + 65536);             // 64 KB
  int*   slot_token = (int*)(ws + 256 + 131072);              // 96 KB
  float* slot_w     = (float*)(ws + 256 + 131072 + 98304);    // 96 KB
  int*   slot_pos   = (int*)(ws + 256 + 131072 + 196608);     // 64 KB
  int4*  table1     = (int4*)(ws + 256 + 131072 + 262144);    // 1.7 KB
  size_t off = 0x80000;
  __bf16* h_bf = (__bf16*)(ws + off); off += (size_t)T_TOK * DDIM * 2;        // 16 MB
  size_t w13_off = off;
  __bf16* w13  = (__bf16*)(ws + off); off += (size_t)9 * 16 * 256 * DDIM * 2; // 75.5 MB
  __bf16* w2c  = (__bf16*)(ws + off); off += (size_t)9 * DDIM * HDIM * 2;     // 37.75 MB
  __bf16* G    = (__bf16*)(ws + off); off += (size_t)NSLOT * HDIM * 2;        // 100.7 MB
  // y_slot overlays w13 (dead after gemm1): 50.3 MB < 75.5 MB
  __bf16* yslot = (__bf16*)(ws + w13_off);

  hipMemsetAsync(meta, 0, 256, stream);

  CvtArgs ca;
  ca.s[0] = h;   ca.d[0] = h_bf;
  ca.s[1] = W1;  ca.d[1] = w13;
  ca.s[2] = sw1; ca.d[2] = w13;
  ca.s[3] = W3;  ca.d[3] = w13;
  ca.s[4] = sw3; ca.d[4] = w13;
  ca.s[5] = W2;  ca.d[5] = w2c;
  ca.s[6] = sw2; ca.d[6] = w2c + (size_t)NEXP * DDIM * HDIM;
  cvt_fused<<<63488, 256, 0, stream>>>(ca);   // 16252928 vec4s / 256

  gate_kernel<<<T_TOK / 4, 256, 0, stream>>>(h, Wg, top_e, top_w, meta);
  build_meta<<<1, 64, 0, stream>>>(meta, table1);
  scatter_kernel<<<T_TOK / 256, 256, 0, stream>>>(top_e, top_w, meta,
                                                  slot_token, slot_w, slot_pos);

  gemm1_k<<<MAX_T * 16, 512, 0, stream>>>(h_bf, w13, table1, slot_token, G);
  gemm2_k<<<MAX_T * 4, 512, 0, stream>>>(G, w2c, table1, yslot);
  combine_kernel<<<T_TOK, 256, 0, stream>>>(yslot, slot_pos, slot_w, y);
}

// Round 3
// 826.255 us; speedup vs baseline: 1.1397x; 1.0132x over previous
//
#include <hip/hip_runtime.h>

// ---------------------------------------------------------------------------
// MoE FFN (SwiGLU, top-2 of 8 + shared expert), MI355X gfx950.
// R7: R6's K-loop bank-conflict fix (chunk swizzle key (row>>1)&3 -> every
//     8-lane ds_read_b128 octet covers all 32 banks) with the epilogue
//     transpose strides reverted to 40/72 elems: R6's 36/68 made odd rows
//     8B-aligned -> misaligned ds_read_b128 -> MEM_VIOL (container death).
// ---------------------------------------------------------------------------

#define T_TOK 8192
#define DDIM  1024
#define HDIM  2048
#define NEXP  8
#define NSLOT 24576        // 2*T routed + T shared
#define NROUTED 16384
#define MAX_T 104          // 256-row tiles: 32 shared + <=71 routed (+pad)
#define NT1 16             // gemm1 K=1024 / 64
#define NT2 32             // gemm2 K=2048 / 64

typedef __attribute__((ext_vector_type(8))) __bf16 bf16x8;
typedef __attribute__((ext_vector_type(4))) __bf16 bf16x4;
typedef __attribute__((ext_vector_type(4))) float  f32x4;

__device__ __forceinline__ void gload16(const void* g, void* l) {
  __builtin_amdgcn_global_load_lds(
      (const __attribute__((address_space(1))) void*)g,
      (__attribute__((address_space(3))) void*)l, 16, 0, 0);
}

#define BAR()   __builtin_amdgcn_s_barrier()
#define VMW10() asm volatile("s_waitcnt vmcnt(10)" ::: "memory")
#define VMW0()  asm volatile("s_waitcnt vmcnt(0)" ::: "memory")
#define LGKM0() asm volatile("s_waitcnt lgkmcnt(0)" ::: "memory")

// ---------------- fused fp32 -> bf16 convert (all 7 tensors, 1 launch) -----
// W1/sw1/W3/sw3 are written into the interleaved w13 layout:
//   row c of B-panel (e,nb):  c = ((h>>5)&3)*64 + sel*32 + (h&31), nb = h>>7
// so that a 64-col wave slice holds [W1 slice | W3 same slice].
struct CvtArgs { const float* s[7]; __bf16* d[7]; };

__global__ __launch_bounds__(256) void cvt_fused(CvtArgs a) {
  // vec4 cumulative bounds: h, W1, sw1, W3, sw3, W2, sw2
  constexpr long cum[8] = {0, 2097152, 6291456, 6815744, 11010048,
                           11534336, 15728640, 16252928};
  long i = (long)blockIdx.x * 256 + threadIdx.x;
  if (i >= cum[7]) return;
  int r = 0;
#pragma unroll
  for (int k = 1; k < 7; k++) if (i >= cum[k]) r = k;
  long o = i - cum[r];
  f32x4 v = ((const f32x4*)a.s[r])[o];
  bf16x4 w;
  w[0] = (__bf16)v[0]; w[1] = (__bf16)v[1];
  w[2] = (__bf16)v[2]; w[3] = (__bf16)v[3];
  if (r >= 1 && r <= 4) {
    int sel  = (r >= 3);
    long e   = (r == 2 || r == 4) ? 8 : (o >> 19);
    long oo  = o & 524287;
    int d4   = (int)(oo & 255);
    int hrow = (int)(oo >> 8) & 2047;
    long c   = ((hrow >> 5) & 3) * 64 + sel * 32 + (hrow & 31);
    long dst = ((e * 16 + (hrow >> 7)) * 256 + c) * 256 + d4;
    ((bf16x4*)a.d[1])[dst] = w;
  } else {
    ((bf16x4*)a.d[r])[o] = w;
  }
}

// ---------------- gate: softmax -> top2 -> renorm (fp32 exact) -------------
__global__ __launch_bounds__(256) void gate_kernel(
    const float* __restrict__ h, const float* __restrict__ Wg,
    int* __restrict__ top_e, float* __restrict__ top_w, int* __restrict__ counts) {
  int wv = threadIdx.x >> 6, lane = threadIdx.x & 63;
  int t = blockIdx.x * 4 + wv;
  const float* x = h + (size_t)t * DDIM;
  float acc[NEXP];
#pragma unroll
  for (int e = 0; e < NEXP; e++) acc[e] = 0.f;
  for (int i = lane; i < DDIM; i += 64) {
    float xv = x[i];
#pragma unroll
    for (int e = 0; e < NEXP; e++) acc[e] = fmaf(xv, Wg[e * DDIM + i], acc[e]);
  }
#pragma unroll
  for (int e = 0; e < NEXP; e++) {
#pragma unroll
    for (int off = 32; off > 0; off >>= 1) acc[e] += __shfl_xor(acc[e], off);
  }
  if (lane == 0) {
    int i1 = 0; float v1 = acc[0];
#pragma unroll
    for (int e = 1; e < NEXP; e++) if (acc[e] > v1) { v1 = acc[e]; i1 = e; }
    int i2 = -1; float v2 = -1e30f;
#pragma unroll
    for (int e = 0; e < NEXP; e++) if (e != i1 && acc[e] > v2) { v2 = acc[e]; i2 = e; }
    float e2 = __expf(v2 - v1);
    float w1 = 1.f / (1.f + e2);
    top_e[2 * t] = i1; top_e[2 * t + 1] = i2;
    top_w[2 * t] = w1; top_w[2 * t + 1] = e2 * w1;
    atomicAdd(&counts[i1], 1);
    atomicAdd(&counts[i2], 1);
  }
}

// ---------------- offsets + tile table (one wave), 256-row tiles -----------
__global__ void build_meta(int* __restrict__ meta, int4* __restrict__ table1) {
  __shared__ int toff[NEXP + 1];
  int lane = threadIdx.x;
  int* counts = meta; int* cursor = meta + 16; int* offsets = meta + 32;
  if (lane == 0) {
    int off = 0, tf = 32;          // shared tiles occupy [0,32)
    for (int e = 0; e < NEXP; e++) {
      offsets[e] = off; cursor[e] = 0;
      toff[e] = tf;
      tf += (counts[e] + 255) >> 8;
      off += counts[e];
    }
    toff[NEXP] = tf;
  }
  __syncthreads();
  for (int i = lane; i < MAX_T; i += 64) {
    if (i < 32) {
      table1[i] = make_int4(NEXP, NROUTED + i * 256, 256, 0);
    } else if (i < toff[NEXP]) {
      int e = 0;
#pragma unroll
      for (int k = 1; k < NEXP; k++) if (i >= toff[k]) e = k;
      int lt = i - toff[e];
      int c = counts[e];
      table1[i] = make_int4(e, offsets[e] + lt * 256, min(256, c - lt * 256), 0);
    } else {
      table1[i] = make_int4(-1, 0, 0, 0);
    }
  }
}

// ---------------- scatter: ballot-ordered per-expert slot lists ------------
__global__ __launch_bounds__(256) void scatter_kernel(
    const int* __restrict__ top_e, const float* __restrict__ top_w,
    int* __restrict__ meta, int* __restrict__ slot_token, float* __restrict__ slot_w,
    int* __restrict__ slot_pos) {
  int t = blockIdx.x * 256 + threadIdx.x;
  int lane = threadIdx.x & 63;
  int* cursor = meta + 16; const int* offsets = meta + 32;
#pragma unroll
  for (int k = 0; k < 2; k++) {
    int e = top_e[2 * t + k];
    unsigned long long same = 0;
#pragma unroll
    for (int ee = 0; ee < NEXP; ee++) {
      unsigned long long m = __ballot(e == ee);
      if (ee == e) same = m;
    }
    int leader = __ffsll((long long)same) - 1;
    int base = 0;
    if (lane == leader) base = atomicAdd(&cursor[e], __popcll(same));
    base = __shfl(base, leader);
    int pos = offsets[e] + base + (int)__popcll(same & ((1ull << lane) - 1ull));
    slot_token[pos] = t; slot_w[pos] = top_w[2 * t + k];
    slot_pos[2 * t + k] = pos;
  }
  slot_token[NROUTED + t] = t;
}

// ---------------- GEMM1: G = silu(A W1^T) * (A W3^T), 8-phase 256x256 ------
// 8 waves (2m x 4n), wave tile 128x64 (= 32 W1-cols + 32 W3-cols of the same
// G slice). LDS: 2 dbuf x {A,B} x 2 kk-halves x [256][32] bf16 = 128 KiB.
__global__ __launch_bounds__(512, 2) void gemm1_k(
    const __bf16* __restrict__ Abase, const __bf16* __restrict__ Wb,
    const int4* __restrict__ table, const int* __restrict__ slot_token,
    __bf16* __restrict__ Gout) {
  int b = blockIdx.x;
  int j = (b & 7) * (MAX_T * 16 / 8) + (b >> 3);   // XCD swizzle (bijective)
  int tile = j >> 4, nb = j & 15;
  int4 te = table[tile];
  if (te.x < 0) return;
  const int expert = te.x, slot0 = te.y, rows = te.z;
  const int tid = threadIdx.x, lane = tid & 63, wave = tid >> 6;
  const int wm = wave >> 2, wn = wave & 3;
  const int ln = lane & 15, q = lane >> 4;

  __shared__ __align__(16) unsigned char lds[131072];

  // staging: thread -> row r0/r0+128, 16B chunk cc; source pre-swizzled.
  // Swizzle: phys chunk cc of row r holds logical chunk cc ^ ((r>>1)&3);
  // every 8-lane ds_read_b128 octet then covers all 32 banks exactly once.
  const int r0 = tid >> 2, cc = tid & 3;
  const int koff = (cc ^ ((r0 >> 1) & 3)) << 3;
  const __bf16* ap0 = Abase + (size_t)slot_token[slot0 + min(r0, rows - 1)] * DDIM + koff;
  const __bf16* ap1 = Abase + (size_t)slot_token[slot0 + min(r0 + 128, rows - 1)] * DDIM + koff;
  const __bf16* bp0 = Wb + (((size_t)expert * 16 + nb) * 256 + r0) * DDIM + koff;
  const __bf16* bp1 = bp0 + 128 * DDIM;
  unsigned char* sb = lds + wave * 1024;

  // frag read bases (swizzled), within a [256][32] kk-half
  const unsigned afo = (wm * 128 + ln) * 64 + ((q ^ ((ln >> 1) & 3)) << 4);
  const unsigned bfo = (wn * 64 + ln) * 64 + ((q ^ ((ln >> 1) & 3)) << 4) + 32768;

  f32x4 acc[8][4] = {};
  bf16x8 afr[4], bfr[4];

  auto SA = [&](int kt, int kk) {
    int ko = min(kt, NT1 - 1) * 64 + kk * 32;
    unsigned char* d = sb + (kt & 1) * 65536 + kk * 16384;
    gload16(ap0 + ko, d); gload16(ap1 + ko, d + 8192);
  };
  auto SB = [&](int kt, int kk) {
    int ko = min(kt, NT1 - 1) * 64 + kk * 32;
    unsigned char* d = sb + (kt & 1) * 65536 + 32768 + kk * 16384;
    gload16(bp0 + ko, d); gload16(bp1 + ko, d + 8192);
  };
  auto RA = [&](int s, int kk, int h) {
#pragma unroll
    for (int i = 0; i < 4; i++)
      afr[i] = *(const bf16x8*)(lds + s * 65536 + kk * 16384 + afo + (h * 4 + i) * 1024);
  };
  auto RB = [&](int s, int kk) {
#pragma unroll
    for (int jj = 0; jj < 4; jj++)
      bfr[jj] = *(const bf16x8*)(lds + s * 65536 + kk * 16384 + bfo + jj * 1024);
  };
  auto MM = [&](int h) {
    __builtin_amdgcn_s_setprio(1);
#pragma unroll
    for (int i = 0; i < 4; i++)
#pragma unroll
      for (int jj = 0; jj < 4; jj++)
        acc[h * 4 + i][jj] = __builtin_amdgcn_mfma_f32_16x16x32_bf16(
            afr[i], bfr[jj], acc[h * 4 + i][jj], 0, 0, 0);
    __builtin_amdgcn_s_setprio(0);
  };

  // prologue: 7 half-tiles in flight; vmcnt(10) leaves 5 newest outstanding
  SA(0, 0); SB(0, 0); SA(0, 1); SB(0, 1);
  SB(1, 0); SA(1, 0); SB(1, 1);
  VMW10(); BAR();

  for (int t = 0; t < NT1; t += 2) {
#pragma unroll
    for (int hb = 0; hb < 2; hb++) {
      const int tt = t + hb, s = hb;
      RB(s, 0); RA(s, 0, 0); SA(tt + 1, 1);
      BAR(); MM(0); BAR();
      RA(s, 0, 1); SB(tt + 2, 0);
      BAR(); MM(1); VMW10(); BAR();
      RB(s, 1); RA(s, 1, 0); SA(tt + 2, 0);
      BAR(); MM(0); BAR();
      RA(s, 1, 1); SB(tt + 2, 1);
      BAR(); MM(1); VMW10(); BAR();
    }
  }

  VMW0(); BAR();   // drain tail garbage stages before LDS reuse

  // epilogue: in-register silu-combine (acc[i][jj] = W1, acc[i][jj+2] = W3,
  // same lane & reg) -> per-wave LDS transpose -> 16B line stores.
  // stride 40 elem = 80 B: keeps every bf16x8 read 16B-aligned.
  __bf16* wbuf = (__bf16*)lds + wave * (128 * 40);
#pragma unroll
  for (int i = 0; i < 8; i++)
#pragma unroll
    for (int jj = 0; jj < 2; jj++)
#pragma unroll
      for (int rg = 0; rg < 4; rg++) {
        float c1 = acc[i][jj][rg], c3 = acc[i][jj + 2][rg];
        float g = (c1 / (1.f + __expf(-c1))) * c3;
        wbuf[(16 * i + 4 * q + rg) * 40 + 16 * jj + ln] = (__bf16)g;
      }
  LGKM0();
  __builtin_amdgcn_sched_barrier(0);
#pragma unroll
  for (int pass = 0; pass < 8; pass++) {
    int rl = pass * 16 + (lane >> 2), ch = lane & 3;
    int grow = wm * 128 + rl;
    if (grow < rows) {
      bf16x8 v = *(const bf16x8*)(wbuf + rl * 40 + ch * 8);
      *(bf16x8*)(Gout + (size_t)(slot0 + grow) * HDIM + nb * 128 + wn * 32 + ch * 8) = v;
    }
  }
}

// ---------------- GEMM2: y_slot = G W2^T, same 8-phase template ------------
__global__ __launch_bounds__(512, 2) void gemm2_k(
    const __bf16* __restrict__ Abase, const __bf16* __restrict__ Bbase,
    const int4* __restrict__ table, __bf16* __restrict__ ys) {
  int b = blockIdx.x;
  int j = (b & 7) * (MAX_T * 4 / 8) + (b >> 3);
  int tile = j >> 2, nb = j & 3;
  int4 te = table[tile];
  if (te.x < 0) return;
  const int expert = te.x, slot0 = te.y, rows = te.z;
  const int tid = threadIdx.x, lane = tid & 63, wave = tid >> 6;
  const int wm = wave >> 2, wn = wave & 3;
  const int ln = lane & 15, q = lane >> 4;

  __shared__ __align__(16) unsigned char lds[131072];

  const int r0 = tid >> 2, cc = tid & 3;
  const int koff = (cc ^ ((r0 >> 1) & 3)) << 3;
  const __bf16* ap0 = Abase + (size_t)(slot0 + min(r0, rows - 1)) * HDIM + koff;
  const __bf16* ap1 = Abase + (size_t)(slot0 + min(r0 + 128, rows - 1)) * HDIM + koff;
  const __bf16* bp0 = Bbase + (size_t)expert * (DDIM * HDIM) +
                      (size_t)(nb * 256 + r0) * HDIM + koff;
  const __bf16* bp1 = bp0 + 128 * HDIM;
  unsigned char* sb = lds + wave * 1024;

  const unsigned afo = (wm * 128 + ln) * 64 + ((q ^ ((ln >> 1) & 3)) << 4);
  const unsigned bfo = (wn * 64 + ln) * 64 + ((q ^ ((ln >> 1) & 3)) << 4) + 32768;

  f32x4 acc[8][4] = {};
  bf16x8 afr[4], bfr[4];

  auto SA = [&](int kt, int kk) {
    int ko = min(kt, NT2 - 1) * 64 + kk * 32;
    unsigned char* d = sb + (kt & 1) * 65536 + kk * 16384;
    gload16(ap0 + ko, d); gload16(ap1 + ko, d + 8192);
  };
  auto SB = [&](int kt, int kk) {
    int ko = min(kt, NT2 - 1) * 64 + kk * 32;
    unsigned char* d = sb + (kt & 1) * 65536 + 32768 + kk * 16384;
    gload16(bp0 + ko, d); gload16(bp1 + ko, d + 8192);
  };
  auto RA = [&](int s, int kk, int h) {
#pragma unroll
    for (int i = 0; i < 4; i++)
      afr[i] = *(const bf16x8*)(lds + s * 65536 + kk * 16384 + afo + (h * 4 + i) * 1024);
  };
  auto RB = [&](int s, int kk) {
#pragma unroll
    for (int jj = 0; jj < 4; jj++)
      bfr[jj] = *(const bf16x8*)(lds + s * 65536 + kk * 16384 + bfo + jj * 1024);
  };
  auto MM = [&](int h) {
    __builtin_amdgcn_s_setprio(1);
#pragma unroll
    for (int i = 0; i < 4; i++)
#pragma unroll
      for (int jj = 0; jj < 4; jj++)
        acc[h * 4 + i][jj] = __builtin_amdgcn_mfma_f32_16x16x32_bf16(
            afr[i], bfr[jj], acc[h * 4 + i][jj], 0, 0, 0);
    __builtin_amdgcn_s_setprio(0);
  };

  SA(0, 0); SB(0, 0); SA(0, 1); SB(0, 1);
  SB(1, 0); SA(1, 0); SB(1, 1);
  VMW10(); BAR();

  for (int t = 0; t < NT2; t += 2) {
#pragma unroll
    for (int hb = 0; hb < 2; hb++) {
      const int tt = t + hb, s = hb;
      RB(s, 0); RA(s, 0, 0); SA(tt + 1, 1);
      BAR(); MM(0); BAR();
      RA(s, 0, 1); SB(tt + 2, 0);
      BAR(); MM(1); VMW10(); BAR();
      RB(s, 1); RA(s, 1, 0); SA(tt + 2, 0);
      BAR(); MM(0); BAR();
      RA(s, 1, 1); SB(tt + 2, 1);
      BAR(); MM(1); VMW10(); BAR();
    }
  }

  VMW0(); BAR();

  // epilogue: 2 m-half passes through a per-wave 64x72 transpose buffer
  // (stride 72 elem = 144 B: bf16x8 reads stay 16B-aligned)
  __bf16* wbuf = (__bf16*)lds + wave * (64 * 72);
#pragma unroll
  for (int hh = 0; hh < 2; hh++) {
#pragma unroll
    for (int i = 0; i < 4; i++)
#pragma unroll
      for (int jj = 0; jj < 4; jj++)
#pragma unroll
        for (int rg = 0; rg < 4; rg++)
          wbuf[(16 * i + 4 * q + rg) * 72 + 16 * jj + ln] =
              (__bf16)acc[hh * 4 + i][jj][rg];
    LGKM0();
    __builtin_amdgcn_sched_barrier(0);
#pragma unroll
    for (int pass = 0; pass < 8; pass++) {
      int rl = pass * 8 + (lane >> 3), ch = lane & 7;
      int grow = wm * 128 + hh * 64 + rl;
      if (grow < rows) {
        bf16x8 v = *(const bf16x8*)(wbuf + rl * 72 + ch * 8);
        *(bf16x8*)(ys + (size_t)(slot0 + grow) * DDIM + nb * 256 + wn * 64 + ch * 8) = v;
      }
    }
    if (hh == 0) { LGKM0(); __builtin_amdgcn_sched_barrier(0); }
  }
}

// ---------------- combine: y[t] = w1*ys[p1] + w2*ys[p2] + ys[shared] -------
__global__ __launch_bounds__(256) void combine_kernel(
    const __bf16* __restrict__ ys, const int* __restrict__ slot_pos,
    const float* __restrict__ slot_w, float* __restrict__ y) {
  int t = blockIdx.x, d = threadIdx.x * 4;
  int p1 = slot_pos[2 * t], p2 = slot_pos[2 * t + 1];
  float w1 = slot_w[p1], w2 = slot_w[p2];
  bf16x4 a = *(const bf16x4*)(ys + (size_t)p1 * DDIM + d);
  bf16x4 bb = *(const bf16x4*)(ys + (size_t)p2 * DDIM + d);
  bf16x4 c = *(const bf16x4*)(ys + (size_t)(NROUTED + t) * DDIM + d);
  f32x4 o;
#pragma unroll
  for (int i = 0; i < 4; i++)
    o[i] = fmaf(w1, (float)a[i], fmaf(w2, (float)bb[i], (float)c[i]));
  *(f32x4*)(y + (size_t)t * DDIM + d) = o;
}

// ---------------------------------------------------------------------------
extern "C" void kernel_launch(void* const* d_in, const int* in_sizes, int n_in,
                              void* d_out, int out_size, void* d_ws, size_t ws_size,
                              hipStream_t stream) {
  const float* h   = (const float*)d_in[0];
  const float* sw1 = (const float*)d_in[1];
  const float* sw2 = (const float*)d_in[2];
  const float* sw3 = (const float*)d_in[3];
  const float* W1  = (const float*)d_in[4];
  const float* W2  = (const float*)d_in[5];
  const float* W3  = (const float*)d_in[6];
  const float* Wg  = (const float*)d_in[7];
  float* y = (float*)d_out;

  char* ws = (char*)d_ws;
  int*   meta       = (int*)ws;                               // 256 B
  int*   top_e      = (int*)(ws + 256);                       // 64 KB
  float* top_w      = (float*)(ws + 256 + 65536);             // 64 KB
  int*   slot_token = (int*)(ws + 256 + 131072);              // 96 KB
  float* slot_w     = (float*)(ws + 256 + 131072 + 98304);    // 96 KB
  int*   slot_pos   = (int*)(ws + 256 + 131072 + 196608);     // 64 KB
  int4*  table1     = (int4*)(ws + 256 + 131072 + 262144);    // 1.7 KB
  size_t off = 0x80000;
  __bf16* h_bf = (__bf16*)(ws + off); off += (size_t)T_TOK * DDIM * 2;        // 16 MB
  size_t w13_off = off;
  __bf16* w13  = (__bf16*)(ws + off); off += (size_t)9 * 16 * 256 * DDIM * 2; // 75.5 MB
  __bf16* w2c  = (__bf16*)(ws + off); off += (size_t)9 * DDIM * HDIM * 2;     // 37.75 MB
  __bf16* G    = (__bf16*)(ws + off); off += (size_t)NSLOT * HDIM * 2;        // 100.7 MB
  // y_slot overlays w13 (dead after gemm1): 50.3 MB < 75.5 MB
  __bf16* yslot = (__bf16*)(ws + w13_off);

  hipMemsetAsync(meta, 0, 256, stream);

  CvtArgs ca;
  ca.s[0] = h;   ca.d[0] = h_bf;
  ca.s[1] = W1;  ca.d[1] = w13;
  ca.s[2] = sw1; ca.d[2] = w13;
  ca.s[3] = W3;  ca.d[3] = w13;
  ca.s[4] = sw3; ca.d[4] = w13;
  ca.s[5] = W2;  ca.d[5] = w2c;
  ca.s[6] = sw2; ca.d[6] = w2c + (size_t)NEXP * DDIM * HDIM;
  cvt_fused<<<63488, 256, 0, stream>>>(ca);   // 16252928 vec4s / 256

  gate_kernel<<<T_TOK / 4, 256, 0, stream>>>(h, Wg, top_e, top_w, meta);
  build_meta<<<1, 64, 0, stream>>>(meta, table1);
  scatter_kernel<<<T_TOK / 256, 256, 0, stream>>>(top_e, top_w, meta,
                                                  slot_token, slot_w, slot_pos);

  gemm1_k<<<MAX_T * 16, 512, 0, stream>>>(h_bf, w13, table1, slot_token, G);
  gemm2_k<<<MAX_T * 4, 512, 0, stream>>>(G, w2c, table1, yslot);
  combine_kernel<<<T_TOK, 256, 0, stream>>>(yslot, slot_pos, slot_w, y);
}